// Round 2
// baseline (587.155 us; speedup 1.0000x reference)
//
#include <hip/hip_runtime.h>

#define KCODES 512
#define DDIM 64
#define MARGIN 6.0e-5f

// Fast screening score: s_fast[k] = e_sq[k] - 2*dot(z, e_k), fmaf 4-acc.
// Common z_sq shift omitted (cancels in comparisons).
__device__ __forceinline__ float fast_score(const float4* __restrict__ e4,
                                            const float* zr, float esqk)
{
    float a0 = 0.f, a1 = 0.f, a2 = 0.f, a3 = 0.f;
    #pragma unroll
    for (int i = 0; i < DDIM / 4; ++i) {
        float4 v = e4[i];
        a0 = fmaf(zr[4*i+0], v.x, a0);
        a1 = fmaf(zr[4*i+1], v.y, a1);
        a2 = fmaf(zr[4*i+2], v.z, a2);
        a3 = fmaf(zr[4*i+3], v.w, a3);
    }
    float dot = (a0 + a1) + (a2 + a3);
    return fmaf(-2.f, dot, esqk);
}

// Bit-exact emulation of the numpy-f32 reference distance:
//   cross = sequential ascending-d, mul then add (NO fma)
//   dist  = fl( fl(z_sq - fl(2*cross)) + e_sq )
__device__ __forceinline__ float np_dist(const float* __restrict__ e,
                                         const float* zr, float zsq, float esqk)
{
    float c = 0.f;
    #pragma unroll
    for (int d = 0; d < DDIM; ++d)
        c = __fadd_rn(c, __fmul_rn(zr[d], e[d]));
    float t = __fsub_rn(zsq, __fmul_rn(2.0f, c));
    return __fadd_rn(t, esqk);
}

__global__ __launch_bounds__(256) void vq_argmin_kernel(
    const float* __restrict__ z, const float* __restrict__ emb, int* __restrict__ out)
{
    __shared__ float esq[KCODES];
    const int t = threadIdx.x;

    // e_sq[k] = np.sum(emb*emb, axis=1): contiguous-axis reduce -> numpy
    // pairwise 8-accumulator pattern, products pre-rounded.
    for (int k = t; k < KCODES; k += 256) {
        const float* e = emb + k * DDIM;
        float r[8];
        #pragma unroll
        for (int j = 0; j < 8; ++j) r[j] = __fmul_rn(e[j], e[j]);
        #pragma unroll
        for (int i = 8; i < DDIM; i += 8)
            #pragma unroll
            for (int j = 0; j < 8; ++j)
                r[j] = __fadd_rn(r[j], __fmul_rn(e[i+j], e[i+j]));
        esq[k] = __fadd_rn(
            __fadd_rn(__fadd_rn(r[0], r[1]), __fadd_rn(r[2], r[3])),
            __fadd_rn(__fadd_rn(r[4], r[5]), __fadd_rn(r[6], r[7])));
    }
    __syncthreads();

    const int p  = blockIdx.x * 256 + t;   // pixel id
    const int b  = p >> 12;
    const int hw = p & 4095;
    const float* zp = z + (size_t)b * (DDIM * 4096) + hw;

    float zr[DDIM];
    #pragma unroll
    for (int d = 0; d < DDIM; ++d) zr[d] = zp[(size_t)d * 4096];

    // z_sq = np.sum(z*z, axis=1): NON-contiguous reduce axis -> numpy
    // accumulates sequentially ascending in d, products pre-rounded.
    float zsq = __fmul_rn(zr[0], zr[0]);
    #pragma unroll
    for (int d = 1; d < DDIM; ++d)
        zsq = __fadd_rn(zsq, __fmul_rn(zr[d], zr[d]));

    // Pass 1: fast scan with top-3 tracking (first-min-wins ordering on i1,i2)
    float m1 = 3.0e38f, m2 = 3.0e38f, m3 = 3.0e38f;
    int   i1 = 0, i2 = 0;
    for (int k = 0; k < KCODES; ++k) {
        const float s = fast_score(reinterpret_cast<const float4*>(emb + k * DDIM), zr, esq[k]);
        const bool b1 = s < m1, b2 = s < m2, b3 = s < m3;
        const float nm3 = b2 ? m2 : (b3 ? s : m3);
        const float nm2 = b1 ? m1 : (b2 ? s : m2);
        const int   ni2 = b1 ? i1 : (b2 ? k : i2);
        const float nm1 = b1 ? s : m1;
        const int   ni1 = b1 ? k : i1;
        m3 = nm3; m2 = nm2; i2 = ni2; m1 = nm1; i1 = ni1;
    }

    int idx = i1;
    if (m2 - m1 < MARGIN) {
        if (m3 - m1 >= MARGIN) {
            // Exactly two candidates {i1,i2}: emulate np-f32 dist for both,
            // compare in ascending-k order (np.argmin first-occurrence).
            const float D1 = np_dist(emb + i1 * DDIM, zr, zsq, esq[i1]);
            const float D2 = np_dist(emb + i2 * DDIM, zr, zsq, esq[i2]);
            const int   ka = (i1 < i2) ? i1 : i2;
            const int   kb = (i1 < i2) ? i2 : i1;
            const float Da = (i1 < i2) ? D1 : D2;
            const float Db = (i1 < i2) ? D2 : D1;
            idx = (Db < Da) ? kb : ka;
        } else {
            // >=3 near-candidates (rare): full rescan, emulate every candidate.
            float bestD = 3.0e38f;
            int   bi = 0;
            bool  found = false;
            for (int k = 0; k < KCODES; ++k) {
                const float s = fast_score(reinterpret_cast<const float4*>(emb + k * DDIM), zr, esq[k]);
                if (s < m1 + MARGIN) {
                    const float Dk = np_dist(emb + k * DDIM, zr, zsq, esq[k]);
                    if (!found || Dk < bestD) { bestD = Dk; bi = k; found = true; }
                }
            }
            idx = bi;
        }
    }
    out[p] = idx;
}

extern "C" void kernel_launch(void* const* d_in, const int* in_sizes, int n_in,
                              void* d_out, int out_size, void* d_ws, size_t ws_size,
                              hipStream_t stream)
{
    const float* z   = (const float*)d_in[0];
    const float* emb = (const float*)d_in[1];
    int* out = (int*)d_out;
    dim3 grid(out_size / 256), block(256);
    hipLaunchKernelGGL(vq_argmin_kernel, grid, block, 0, stream, z, emb, out);
}

// Round 3
// 117.780 us; speedup vs baseline: 4.9852x; 4.9852x over previous
//
#include <hip/hip_runtime.h>

#define KCODES 512
#define DDIM 64

typedef __attribute__((ext_vector_type(8))) short bf16x8;
typedef __attribute__((ext_vector_type(4))) float f32x4;

// Split f32 into bf16 hi + bf16 lo (RNE). z - bf16(z) is exact in f32 (Sterbenz).
__device__ __forceinline__ void bf16_split(float v, unsigned short& hi, unsigned short& lo) {
    unsigned u = __float_as_uint(v);
    unsigned r = u + 0x7fffu + ((u >> 16) & 1u);
    hi = (unsigned short)(r >> 16);
    float hf = __uint_as_float(((unsigned)hi) << 16);
    float l = v - hf;
    unsigned u2 = __float_as_uint(l);
    unsigned r2 = u2 + 0x7fffu + ((u2 >> 16) & 1u);
    lo = (unsigned short)(r2 >> 16);
}

// Bit-exact emulation of the numpy-f32 reference distance (verified round 2):
//   z_sq: sequential ascending-d, pre-rounded squares (non-contiguous axis reduce)
//   cross: sequential ascending-d, mul then add (no fma)
//   dist = fl( fl(z_sq - fl(2*cross)) + esq )
__device__ __forceinline__ float np_dist_strided(const float* __restrict__ zp,
                                                 const float* __restrict__ e, float esqk) {
    float zq = 0.f, cr = 0.f;
    #pragma unroll 8
    for (int d = 0; d < DDIM; ++d) {
        float zv = zp[(size_t)d * 4096];
        zq = __fadd_rn(zq, __fmul_rn(zv, zv));
        cr = __fadd_rn(cr, __fmul_rn(zv, e[d]));
    }
    return __fadd_rn(__fsub_rn(zq, __fmul_rn(2.0f, cr)), esqk);
}

__global__ __launch_bounds__(256) void vq_argmin_kernel(
    const float* __restrict__ z, const float* __restrict__ emb, int* __restrict__ out)
{
    __shared__ unsigned short ehi[128 * 64];  // 16 KB, XOR-swizzled bf16 hi
    __shared__ unsigned short elo[128 * 64];  // 16 KB, XOR-swizzled bf16 lo
    __shared__ float esq[KCODES];             // 2 KB (numpy-pairwise f32)

    const int t    = threadIdx.x;
    const int lane = t & 63;
    const int w    = t >> 6;       // wave id 0..3
    const int g    = lane >> 4;    // lane group 0..3
    const int p16  = lane & 15;    // pixel-in-set / code-in-tile

    // ---- esq[k] = np.sum(emb*emb, axis=1): contiguous axis -> pairwise-8 (round-2 verified)
    for (int k = t; k < KCODES; k += 256) {
        const float* e = emb + k * DDIM;
        float r[8];
        #pragma unroll
        for (int j = 0; j < 8; ++j) r[j] = __fmul_rn(e[j], e[j]);
        #pragma unroll
        for (int i = 8; i < DDIM; i += 8)
            #pragma unroll
            for (int j = 0; j < 8; ++j)
                r[j] = __fadd_rn(r[j], __fmul_rn(e[i + j], e[i + j]));
        esq[k] = __fadd_rn(
            __fadd_rn(__fadd_rn(r[0], r[1]), __fadd_rn(r[2], r[3])),
            __fadd_rn(__fadd_rn(r[4], r[5]), __fadd_rn(r[6], r[7])));
    }

    // ---- pixel mapping: WG covers 256 consecutive pixels, wave covers 64
    const int P0  = blockIdx.x * 256;
    const int bb  = P0 >> 12;
    const int hwW = (P0 & 4095) + w * 64;
    const float* zbase = z + (size_t)bb * (DDIM * 4096);

    // ---- B-fragments: 4 sets x 2 K-chunks, hi+lo splits; per-pixel sum|z|
    bf16x8 zh[4][2], zl[4][2];
    float  sab[4];
    #pragma unroll
    for (int s = 0; s < 4; ++s) {
        sab[s] = 0.f;
        #pragma unroll
        for (int c = 0; c < 2; ++c) {
            #pragma unroll
            for (int j = 0; j < 8; ++j) {
                int d = g * 8 + j + c * 32;
                float v = zbase[(size_t)d * 4096 + hwW + s * 16 + p16];
                sab[s] += fabsf(v);
                unsigned short h, l;
                bf16_split(v, h, l);
                zh[s][c][j] = (short)h;
                zl[s][c][j] = (short)l;
            }
        }
    }

    // ---- top-3 state per set
    float m1[4], m2[4], m3[4];
    int   i1[4], i2[4];
    #pragma unroll
    for (int s = 0; s < 4; ++s) { m1[s] = m2[s] = m3[s] = 3.0e38f; i1[s] = i2[s] = 0; }

    const int rx  = p16 & 7;          // swizzle class (row&7 == p16&7 since tiles are 16 rows)
    const int jj0 = (g) ^ rx;         // chunk-0 slot
    const int jj1 = (4 + g) ^ rx;     // chunk-1 slot
    const int g4  = g * 4;

    // ---- 4 passes of 128 codes staged to LDS as bf16 hi/lo (swizzled)
    for (int pp = 0; pp < 4; ++pp) {
        __syncthreads();   // previous pass reads done
        {
            // thread t stages row r = t>>1, d-half (t&1)*32
            const int r  = t >> 1;
            const int dh = (t & 1) * 32;
            const float* src = emb + (pp * 128 + r) * DDIM + dh;
            #pragma unroll
            for (int q = 0; q < 4; ++q) {
                bf16x8 hh, ll;
                #pragma unroll
                for (int j = 0; j < 8; ++j) {
                    unsigned short h, l;
                    bf16_split(src[q * 8 + j], h, l);
                    hh[j] = (short)h; ll[j] = (short)l;
                }
                int jidx = (dh >> 3) + q;                       // 0..7
                int idx  = r * 64 + ((jidx ^ (r & 7)) << 3);    // swizzled
                *(bf16x8*)&ehi[idx] = hh;
                *(bf16x8*)&elo[idx] = ll;
            }
        }
        __syncthreads();

        // ---- score 8 tiles of 16 codes
        #pragma unroll
        for (int tt = 0; tt < 8; ++tt) {
            const int rowbase = tt * 16 + p16;
            const int ib0 = rowbase * 64 + jj0 * 8;
            const int ib1 = rowbase * 64 + jj1 * 8;
            bf16x8 ah0 = *(const bf16x8*)&ehi[ib0];
            bf16x8 ah1 = *(const bf16x8*)&ehi[ib1];
            bf16x8 al0 = *(const bf16x8*)&elo[ib0];
            bf16x8 al1 = *(const bf16x8*)&elo[ib1];
            const float* eq = &esq[pp * 128 + tt * 16 + g4];
            float e0 = eq[0], e1 = eq[1], e2 = eq[2], e3 = eq[3];
            const int cb = pp * 128 + tt * 16;  // + g4 + r below

            #pragma unroll
            for (int s = 0; s < 4; ++s) {
                f32x4 acc = {0.f, 0.f, 0.f, 0.f};
                acc = __builtin_amdgcn_mfma_f32_16x16x32_bf16(ah0, zh[s][0], acc, 0, 0, 0);
                acc = __builtin_amdgcn_mfma_f32_16x16x32_bf16(ah1, zh[s][1], acc, 0, 0, 0);
                acc = __builtin_amdgcn_mfma_f32_16x16x32_bf16(al0, zh[s][0], acc, 0, 0, 0);
                acc = __builtin_amdgcn_mfma_f32_16x16x32_bf16(al1, zh[s][1], acc, 0, 0, 0);
                acc = __builtin_amdgcn_mfma_f32_16x16x32_bf16(ah0, zl[s][0], acc, 0, 0, 0);
                acc = __builtin_amdgcn_mfma_f32_16x16x32_bf16(ah1, zl[s][1], acc, 0, 0, 0);
                #pragma unroll
                for (int r = 0; r < 4; ++r) {
                    float er = (r == 0) ? e0 : (r == 1) ? e1 : (r == 2) ? e2 : e3;
                    float sc = fmaf(-2.0f, acc[r], er);
                    int   cd = cb + g4 + r;
                    bool b1 = sc < m1[s];
                    bool b2 = sc < m2[s];
                    m3[s] = b2 ? m2[s] : fminf(m3[s], sc);
                    m2[s] = b1 ? m1[s] : fminf(m2[s], sc);
                    i2[s] = b1 ? i1[s] : (b2 ? cd : i2[s]);
                    m1[s] = fminf(m1[s], sc);
                    i1[s] = b1 ? cd : i1[s];
                }
            }
        }
    }

    // ---- merge the 4 replica lane-groups per set (butterfly xor 16, 32)
    #pragma unroll
    for (int s = 0; s < 4; ++s) {
        #pragma unroll
        for (int st = 0; st < 2; ++st) {
            int mask = 16 << st;
            float om1 = __shfl_xor(m1[s], mask); int oi1 = __shfl_xor(i1[s], mask);
            float om2 = __shfl_xor(m2[s], mask); int oi2 = __shfl_xor(i2[s], mask);
            float om3 = __shfl_xor(m3[s], mask);
            float osa = __shfl_xor(sab[s], mask);
            sab[s] += osa;
            bool  take1 = om1 < m1[s];
            float hi  = take1 ? m1[s] : om1;  int hii = take1 ? i1[s] : oi1;
            float n1  = take1 ? om1 : m1[s];  int ni1 = take1 ? oi1 : i1[s];
            float mn2 = fminf(m2[s], om2);    int mi2 = (om2 < m2[s]) ? oi2 : i2[s];
            bool  sec = hi < mn2;
            float n2  = sec ? hi : mn2;       int ni2 = sec ? hii : mi2;
            float n3  = fminf(fmaxf(hi, mn2), fminf(m3[s], om3));
            m1[s] = n1; i1[s] = ni1; m2[s] = n2; i2[s] = ni2; m3[s] = n3;
        }
    }

    // ---- lane owns pixel (set=g, p16): select that set's merged state
    float M1v = (g == 0) ? m1[0] : (g == 1) ? m1[1] : (g == 2) ? m1[2] : m1[3];
    float M2v = (g == 0) ? m2[0] : (g == 1) ? m2[1] : (g == 2) ? m2[2] : m2[3];
    float M3v = (g == 0) ? m3[0] : (g == 1) ? m3[1] : (g == 2) ? m3[2] : m3[3];
    float SA  = (g == 0) ? sab[0] : (g == 1) ? sab[1] : (g == 2) ? sab[2] : sab[3];
    int   I1  = (g == 0) ? i1[0] : (g == 1) ? i1[1] : (g == 2) ? i1[2] : i1[3];
    int   I2  = (g == 0) ? i2[0] : (g == 1) ? i2[1] : (g == 2) ? i2[2] : i2[3];

    // sound screen margin: split-bf16 product error + np-emulation rounding slack
    const float MARG = SA * 2.0e-7f + 2.5e-5f;
    const bool  f2 = (M2v - M1v) < MARG;
    const bool  f3 = (M3v - M1v) < MARG;

    const float* zrow = zbase + hwW + lane;   // this lane's pixel column
    int idx = I1;

    if (f2 && !f3) {
        // exactly two candidates: bit-exact np rescore, first-occurrence wins
        int a = min(I1, I2), b = max(I1, I2);
        float Da = np_dist_strided(zrow, emb + a * DDIM, esq[a]);
        float Db = np_dist_strided(zrow, emb + b * DDIM, esq[b]);
        idx = (Db < Da) ? b : a;
    }

    // >=3 near-candidates (rare): wave-cooperative full np rescan for that pixel
    unsigned long long bal = __ballot(f3);
    while (bal) {
        int pix = __ffsll((long long)bal) - 1;
        bal &= bal - 1;
        const float* zf = zbase + hwW + pix;   // uniform across lanes
        float bD = 3.0e38f; int bC = 0;
        #pragma unroll
        for (int j = 0; j < 8; ++j) {
            int c = j * 64 + lane;
            float D = np_dist_strided(zf, emb + c * DDIM, esq[c]);
            if (D < bD) { bD = D; bC = c; }   // ascending c: first-win
        }
        #pragma unroll
        for (int mk = 1; mk < 64; mk <<= 1) {
            float oD = __shfl_xor(bD, mk);
            int   oC = __shfl_xor(bC, mk);
            if (oD < bD || (oD == bD && oC < bC)) { bD = oD; bC = oC; }
        }
        if (lane == pix) idx = bC;
    }

    out[P0 + w * 64 + lane] = idx;
}

extern "C" void kernel_launch(void* const* d_in, const int* in_sizes, int n_in,
                              void* d_out, int out_size, void* d_ws, size_t ws_size,
                              hipStream_t stream)
{
    const float* z   = (const float*)d_in[0];
    const float* emb = (const float*)d_in[1];
    int* out = (int*)d_out;
    dim3 grid(out_size / 256), block(256);
    hipLaunchKernelGGL(vq_argmin_kernel, grid, block, 0, stream, z, emb, out);
}